// Round 6
// baseline (1064.145 us; speedup 1.0000x reference)
//
#include <hip/hip_runtime.h>

#define B_ 256
#define C_ 64
#define L_ 512
#define CIN_ 82
#define NFREQ_ 9
#define EMB_ 256
#define NLAB_ 10
#define PT_ 37056
#define OFF_BH 16384
#define OFF_WL 16448
#define OFF_BL 20544
#define OFF_WS 20608
#define OFF_BS 36992
#define PI_F 3.14159265358979323846f

typedef short bh8 __attribute__((ext_vector_type(8)));   // 8 bf16 (raw bits)
typedef float f32x4 __attribute__((ext_vector_type(4)));

__device__ inline float lrelu(float v){ return v > 0.f ? v : 0.2f*v; }

__device__ inline unsigned short f2bf(float f){
  unsigned u = __float_as_uint(f);
  u += 0x7FFFu + ((u >> 16) & 1u);      // RNE
  return (unsigned short)(u >> 16);
}
__device__ inline float bf2f(unsigned short u){
  return __uint_as_float((unsigned)u << 16);
}
__device__ inline unsigned pk2(float a, float b){
  return (unsigned)f2bf(a) | ((unsigned)f2bf(b) << 16);
}
__device__ inline bh8 cvt8(float4 a, float4 b){
  bh8 r;
  r[0]=(short)f2bf(a.x); r[1]=(short)f2bf(a.y); r[2]=(short)f2bf(a.z); r[3]=(short)f2bf(a.w);
  r[4]=(short)f2bf(b.x); r[5]=(short)f2bf(b.y); r[6]=(short)f2bf(b.z); r[7]=(short)f2bf(b.w);
  return r;
}
// 16B fragment via two 8B loads (for 8B-aligned LDS rows)
__device__ inline bh8 ld8(const unsigned short* p){
  union { uint2 u[2]; bh8 v; } t;
  t.u[0] = *(const uint2*)p; t.u[1] = *(const uint2*)(p+4);
  return t.v;
}

// k-permutation for wh/ws sections: orig i = br*64+c  ->  k = 4c+br
__device__ inline int perm_j(int j){
  if (j < OFF_BH){ int m = j >> 8, i = j & 255; return (m << 8) + ((i & 63) << 2) + (i >> 6); }
  if (j >= OFF_WS && j < OFF_BS){
    int jj = j - OFF_WS; int m = jj >> 8, i = jj & 255;
    return OFF_WS + (m << 8) + ((i & 63) << 2) + (i >> 6);
  }
  return j;
}

// ---------------- yemb: normalize(fc_w[:,y]+fc_b) -> bf16 [b][e]; zero loss slot
__global__ __launch_bounds__(256) void k_yemb(const float* __restrict__ fc_w,
    const float* __restrict__ fc_b, const int* __restrict__ y,
    unsigned short* __restrict__ ybf, float* __restrict__ out){
  int b = blockIdx.x, e = threadIdx.x;
  int lab = y[b];
  float v = fc_w[e*NLAB_ + lab] + fc_b[e];
  __shared__ float red[256];
  red[e] = v*v; __syncthreads();
  for (int s = 128; s; s >>= 1){ if (e < s) red[e] += red[e+s]; __syncthreads(); }
  float nrm = fmaxf(sqrtf(red[0]), 1e-12f);
  ybf[(size_t)b*EMB_ + e] = f2bf(v / nrm);
  if (b == 0 && e == 0) out[B_*L_] = 0.f;
}

// ---------------- hyper (MFMA): p_bf[b][perm(j)] = bf16(yemb[b][:] . hw[j][:] + hb[j])
__global__ __launch_bounds__(256) void k_hyper(const float* __restrict__ hw,
    const float* __restrict__ hb, const unsigned short* __restrict__ ybf,
    unsigned short* __restrict__ p_bf){
  int tid = threadIdx.x;
  int wid = tid >> 6, lane = tid & 63, col = lane & 15, quad = lane >> 4;
  int j = blockIdx.x*64 + wid*16 + col;
  f32x4 acc[16];
  f32x4 z4 = {0.f,0.f,0.f,0.f};
  #pragma unroll
  for (int i = 0; i < 16; i++) acc[i] = z4;
  for (int k0 = 0; k0 < 256; k0 += 32){
    const float* hp = hw + (size_t)j*EMB_ + k0 + quad*8;
    bh8 bf = cvt8(*(const float4*)hp, *(const float4*)(hp+4));
    #pragma unroll
    for (int mt = 0; mt < 16; mt++){
      bh8 af = *(const bh8*)&ybf[(size_t)(mt*16 + col)*EMB_ + k0 + quad*8];
      acc[mt] = __builtin_amdgcn_mfma_f32_16x16x32_bf16(af, bf, acc[mt], 0, 0, 0);
    }
  }
  float hbv = hb[j];
  int jd = perm_j(j);
  #pragma unroll
  for (int mt = 0; mt < 16; mt++){
    int b0 = mt*16 + quad*4;
    #pragma unroll
    for (int r = 0; r < 4; r++)
      p_bf[(size_t)(b0 + r)*PT_ + jd] = f2bf(acc[mt][r] + hbv);
  }
}

// positional encoding value (raw)
__device__ inline float pe_raw(int fi, int l){
  if (fi < NFREQ_) return __sinf(PI_F / (float)(1 << fi) * (float)l);
  return __cosf(PI_F / (float)(1 << (fi - NFREQ_)) * (float)l);
}

// ---------------- conv_in1 (MFMA): t1bf[b][l][m] = bf16(lrelu(conv3(leaky(xcat), in_w0)+in_b0))
// grid (B,4). xT stride 104 (13x16B, conflict-free b128); weights tap-interleaved stride 296 (37x16B).
__global__ __launch_bounds__(256) void k_conv_in1(const float* __restrict__ codes,
    const float* __restrict__ w0, const float* __restrict__ b0,
    unsigned short* __restrict__ t1bf){
  int b = blockIdx.x, l0 = blockIdx.y*128, tid = threadIdx.x;
  int wid = tid>>6, lane = tid&63, col = lane&15, quad = lane>>4;
  __shared__ __attribute__((aligned(16))) unsigned short xT[132][104];   // row r <-> l = l0-1+r
  __shared__ __attribute__((aligned(16))) unsigned short wAi[64][296];   // [m][t*96+cin]
  for (int i = tid; i < 64*288; i += 256){
    int m = i / 288, rem = i % 288, t = rem / 96, cin = rem % 96;
    wAi[m][t*96 + cin] = (cin < CIN_) ? f2bf(w0[(size_t)m*(CIN_*3) + cin*3 + t]) : (unsigned short)0;
  }
  const float* cb = codes + (size_t)b*C_*L_;
  for (int i = tid; i < 96*33; i += 256){
    int c = i / 33, g = i % 33;
    #pragma unroll
    for (int r2 = 0; r2 < 4; r2++){
      int row = 4*g + r2;
      int l = l0 - 1 + row;
      float xv = 0.f;
      if (l >= 0 && l < L_){
        if (c < C_) xv = cb[(size_t)c*L_ + l];
        else if (c < CIN_) xv = pe_raw(c - C_, l);
      }
      xT[row][c] = f2bf(lrelu(xv));
    }
  }
  __syncthreads();
  f32x4 z4 = {0.f,0.f,0.f,0.f};
  f32x4 acc[8];
  #pragma unroll
  for (int i = 0; i < 8; i++) acc[i] = z4;
  #pragma unroll
  for (int t = 0; t < 3; t++){
    #pragma unroll
    for (int k0 = 0; k0 < 96; k0 += 32){
      bh8 bfr[2];
      #pragma unroll
      for (int nt = 0; nt < 2; nt++)
        bfr[nt] = *(const bh8*)&xT[wid*32 + nt*16 + col + t][k0 + quad*8];
      #pragma unroll
      for (int mt = 0; mt < 4; mt++){
        bh8 af = *(const bh8*)&wAi[mt*16 + col][t*96 + k0 + quad*8];
        #pragma unroll
        for (int nt = 0; nt < 2; nt++)
          acc[mt*2+nt] = __builtin_amdgcn_mfma_f32_16x16x32_bf16(af, bfr[nt], acc[mt*2+nt], 0,0,0);
      }
    }
  }
  #pragma unroll
  for (int mt = 0; mt < 4; mt++){
    int f0 = mt*16 + quad*4;
    float q0 = b0[f0], q1 = b0[f0+1], q2 = b0[f0+2], q3 = b0[f0+3];
    #pragma unroll
    for (int nt = 0; nt < 2; nt++){
      int l = l0 + wid*32 + nt*16 + col;
      f32x4 a = acc[mt*2+nt];
      uint2 o = { pk2(lrelu(a[0]+q0), lrelu(a[1]+q1)),
                  pk2(lrelu(a[2]+q2), lrelu(a[3]+q3)) };
      *(uint2*)&t1bf[((size_t)b*L_ + l)*64 + f0] = o;
    }
  }
}

// ---------------- conv_in2 (MFMA): x = conv1x1(xcat, in_ws) + 0.1*(conv3(leaky(t1), in_w1)+in_b1)
// grid (B,4). Strides 100/100/68, fragments via ld8 (8B-aligned, conflict-free b64 pattern).
__global__ __launch_bounds__(256) void k_conv_in2(const float* __restrict__ codes,
    const float* __restrict__ wsp, const float* __restrict__ w1, const float* __restrict__ b1,
    const unsigned short* __restrict__ t1bf, float* __restrict__ x){
  int b = blockIdx.x, l0 = blockIdx.y*128, tid = threadIdx.x;
  int wid = tid>>6, lane = tid&63, col = lane&15, quad = lane>>4;
  __shared__ __attribute__((aligned(16))) unsigned short xT[128][100];   // raw xcat
  __shared__ __attribute__((aligned(16))) unsigned short wsA[64][100];
  __shared__ __attribute__((aligned(16))) unsigned short w1A[3][64][68];
  for (int i = tid; i < 64*96; i += 256){
    int m = i / 96, cin = i % 96;
    wsA[m][cin] = (cin < CIN_) ? f2bf(wsp[(size_t)m*CIN_ + cin]) : (unsigned short)0;
  }
  for (int i = tid; i < 64*64; i += 256){
    int m = i >> 6, cin = i & 63;
    const float* s = w1 + (size_t)m*192 + cin*3;
    w1A[0][m][cin] = f2bf(s[0]); w1A[1][m][cin] = f2bf(s[1]); w1A[2][m][cin] = f2bf(s[2]);
  }
  const float* cb = codes + (size_t)b*C_*L_;
  for (int i = tid; i < 96*32; i += 256){
    int c = i / 32, g = i % 32;
    int lg = l0 + 4*g;
    #pragma unroll
    for (int r2 = 0; r2 < 4; r2++){
      int l = lg + r2;
      float xv;
      if (c < C_) xv = cb[(size_t)c*L_ + l];
      else if (c < CIN_) xv = pe_raw(c - C_, l);
      else xv = 0.f;
      xT[4*g + r2][c] = f2bf(xv);
    }
  }
  __syncthreads();
  f32x4 z4 = {0.f,0.f,0.f,0.f};
  f32x4 accS[8], accD[8];
  #pragma unroll
  for (int i = 0; i < 8; i++){ accS[i] = z4; accD[i] = z4; }
  // 1x1 over raw xcat, K=96
  #pragma unroll
  for (int k0 = 0; k0 < 96; k0 += 32){
    bh8 bfr[2];
    #pragma unroll
    for (int nt = 0; nt < 2; nt++)
      bfr[nt] = ld8(&xT[wid*32 + nt*16 + col][k0 + quad*8]);
    #pragma unroll
    for (int mt = 0; mt < 4; mt++){
      bh8 af = ld8(&wsA[mt*16 + col][k0 + quad*8]);
      #pragma unroll
      for (int nt = 0; nt < 2; nt++)
        accS[mt*2+nt] = __builtin_amdgcn_mfma_f32_16x16x32_bf16(af, bfr[nt], accS[mt*2+nt], 0,0,0);
    }
  }
  // conv3 over leaky(t1) (already leaky'd in t1bf), K=64, B-frags from global
  bh8 zz8 = {0,0,0,0,0,0,0,0};
  #pragma unroll
  for (int t = 0; t < 3; t++){
    #pragma unroll
    for (int k0 = 0; k0 < 64; k0 += 32){
      bh8 bfr[2];
      #pragma unroll
      for (int nt = 0; nt < 2; nt++){
        int l = l0 + wid*32 + nt*16 + col + t - 1;
        bfr[nt] = (l >= 0 && l < L_)
          ? *(const bh8*)&t1bf[((size_t)b*L_ + l)*64 + k0 + quad*8] : zz8;
      }
      #pragma unroll
      for (int mt = 0; mt < 4; mt++){
        bh8 af = ld8(&w1A[t][mt*16 + col][k0 + quad*8]);
        #pragma unroll
        for (int nt = 0; nt < 2; nt++)
          accD[mt*2+nt] = __builtin_amdgcn_mfma_f32_16x16x32_bf16(af, bfr[nt], accD[mt*2+nt], 0,0,0);
      }
    }
  }
  #pragma unroll
  for (int mt = 0; mt < 4; mt++){
    int f0 = mt*16 + quad*4;
    float q0 = b1[f0], q1 = b1[f0+1], q2 = b1[f0+2], q3 = b1[f0+3];
    #pragma unroll
    for (int nt = 0; nt < 2; nt++){
      int l = l0 + wid*32 + nt*16 + col;
      f32x4 s = accS[mt*2+nt], d = accD[mt*2+nt];
      size_t base = ((size_t)b*C_ + f0)*L_ + l;
      x[base]        = s[0] + 0.1f*(d[0] + q0);
      x[base + L_]   = s[1] + 0.1f*(d[1] + q1);
      x[base + 2*L_] = s[2] + 0.1f*(d[2] + q2);
      x[base + 3*L_] = s[3] + 0.1f*(d[3] + q3);
    }
  }
}

// ---------------- k_iter: fused inst-norm + sin-sobel (shuffle) + hypernet GEMMs + x update
// grid (B,2); 256 thr; l-window = blockIdx.y*256. K permuted as k=4c+br.
__global__ __launch_bounds__(256, 2) void k_iter(float* __restrict__ x,
    const unsigned short* __restrict__ p_bf, const float* __restrict__ leak){
  int b = blockIdx.x, yblk = blockIdx.y, tid = threadIdx.x;
  int wid = tid >> 6, lane = tid & 63, col = lane & 15, quad = lane >> 4;
  int l0 = yblk * 256;
  const unsigned short* pb = p_bf + (size_t)b*PT_;
  const float* xb = x + (size_t)b*C_*L_;

  __shared__ __attribute__((aligned(16))) unsigned short fch[256][40];  // [l_local][32k + pad]
  __shared__ __attribute__((aligned(16))) unsigned short h_t[256][72];
  __shared__ float sm[64], sr[64];

  // ---- stats: mean/rstd per channel
  for (int t = 0; t < 16; t++){
    int c = t*4 + wid;
    const float* xr = xb + (size_t)c*L_ + lane*8;
    float4 v0 = *(const float4*)xr, v1 = *(const float4*)(xr+4);
    float s1 = v0.x+v0.y+v0.z+v0.w + v1.x+v1.y+v1.z+v1.w;
    float s2 = v0.x*v0.x+v0.y*v0.y+v0.z*v0.z+v0.w*v0.w
             + v1.x*v1.x+v1.y*v1.y+v1.z*v1.z+v1.w*v1.w;
    #pragma unroll
    for (int m = 32; m; m >>= 1){ s1 += __shfl_xor(s1, m); s2 += __shfl_xor(s2, m); }
    if (lane == 0){
      float mean = s1 * (1.f/512.f);
      sm[c] = mean;
      sr[c] = rsqrtf(s2*(1.f/512.f) - mean*mean + 1e-5f);
    }
  }
  __syncthreads();

  f32x4 zz4 = {0.f,0.f,0.f,0.f};
  f32x4 acc_h[16], acc_s[16];
  #pragma unroll
  for (int i = 0; i < 16; i++){ acc_h[i] = zz4; acc_s[i] = zz4; }

  int yy = lane & 7, zzd = lane >> 3;
  float wm = (yy > 0) ? 1.f : 0.f, wp = (yy < 7) ? 1.f : 0.f;
  float qm = (zzd > 0) ? 1.f : 0.f, qp = (zzd < 7) ? 1.f : 0.f;
  bool active = ((lane >> 5) == yblk);

  for (int ch = 0; ch < 8; ch++){
    // ---- produce chunk: 8 channels (c = ch*8 .. ch*8+7), 2 rounds x 4 waves
    #pragma unroll
    for (int rr = 0; rr < 2; rr++){
      int cc = rr*4 + wid;          // 0..7 within chunk
      int c = ch*8 + cc;
      const float* xr = xb + (size_t)c*L_ + lane*8;
      float4 v0 = *(const float4*)xr, v1 = *(const float4*)(xr+4);
      float r8[8] = { v0.x, v0.y, v0.z, v0.w, v1.x, v1.y, v1.z, v1.w };
      float mean = sm[c], rstd = sr[c];
      float xn[8];
      #pragma unroll
      for (int i = 0; i < 8; i++) xn[i] = (r8[i] - mean) * rstd;
      float A[8], Bv[8];
      A[0] = 2.f*xn[0] + xn[1];  Bv[0] = xn[1];
      #pragma unroll
      for (int i = 1; i < 7; i++){ A[i] = xn[i-1] + 2.f*xn[i] + xn[i+1]; Bv[i] = xn[i+1] - xn[i-1]; }
      A[7] = xn[6] + 2.f*xn[7];  Bv[7] = -xn[6];
      float Cv[8], Dv[8], Ev[8];
      #pragma unroll
      for (int i = 0; i < 8; i++){
        float am = __shfl_up(A[i], 1)*wm,  ap = __shfl_down(A[i], 1)*wp;
        float bm = __shfl_up(Bv[i], 1)*wm, bp = __shfl_down(Bv[i], 1)*wp;
        Cv[i] = am + 2.f*A[i] + ap;
        Dv[i] = ap - am;
        Ev[i] = bm + 2.f*Bv[i] + bp;
      }
      uint2 val[8];
      #pragma unroll
      for (int i = 0; i < 8; i++){
        float cm = __shfl_up(Cv[i], 8)*qm, cp = __shfl_down(Cv[i], 8)*qp;
        float dm = __shfl_up(Dv[i], 8)*qm, dp = __shfl_down(Dv[i], 8)*qp;
        float em = __shfl_up(Ev[i], 8)*qm, ep = __shfl_down(Ev[i], 8)*qp;
        float G0 = cp - cm;
        float G1 = dm + 2.f*Dv[i] + dp;
        float G2 = em + 2.f*Ev[i] + ep;
        val[i].x = pk2(xn[i], __sinf(G0));
        val[i].y = pk2(__sinf(G1), __sinf(G2));
      }
      if (active){
        int lrow = (lane & 31) * 8;
        #pragma unroll
        for (int j = 0; j < 8; j++){
          int i = (j + yy) & 7;      // stagger to spread LDS banks
          *(uint2*)&fch[lrow + i][cc*4] = val[i];
        }
      }
    }
    __syncthreads();
    // ---- consume chunk: one K=32 MFMA step
    bh8 bfr[4];
    #pragma unroll
    for (int nt = 0; nt < 4; nt++)
      bfr[nt] = *(const bh8*)&fch[wid*64 + nt*16 + col][quad*8];
    #pragma unroll
    for (int mt = 0; mt < 4; mt++){
      int m = mt*16 + col;
      bh8 ah = *(const bh8*)&pb[(size_t)m*256 + ch*32 + quad*8];
      bh8 aw = *(const bh8*)&pb[OFF_WS + (size_t)m*256 + ch*32 + quad*8];
      #pragma unroll
      for (int nt = 0; nt < 4; nt++){
        acc_h[mt*4+nt] = __builtin_amdgcn_mfma_f32_16x16x32_bf16(ah, bfr[nt], acc_h[mt*4+nt], 0, 0, 0);
        acc_s[mt*4+nt] = __builtin_amdgcn_mfma_f32_16x16x32_bf16(aw, bfr[nt], acc_s[mt*4+nt], 0, 0, 0);
      }
    }
    __syncthreads();
  }

  // ---- h = leaky(acc_h + bh) -> h_t
  #pragma unroll
  for (int mt = 0; mt < 4; mt++){
    int f0 = mt*16 + quad*4;
    float bh0 = bf2f(pb[OFF_BH+f0]), bh1 = bf2f(pb[OFF_BH+f0+1]);
    float bh2 = bf2f(pb[OFF_BH+f0+2]), bh3 = bf2f(pb[OFF_BH+f0+3]);
    #pragma unroll
    for (int nt = 0; nt < 4; nt++){
      int n = wid*64 + nt*16 + col;
      f32x4 a = acc_h[mt*4+nt];
      uint2 o = { pk2(lrelu(a[0]+bh0), lrelu(a[1]+bh1)),
                  pk2(lrelu(a[2]+bh2), lrelu(a[3]+bh3)) };
      *(uint2*)&h_t[n][f0] = o;
    }
  }
  __syncthreads();
  // ---- phase 2: acc2 = wl @ h
  f32x4 acc2[16];
  #pragma unroll
  for (int i = 0; i < 16; i++) acc2[i] = zz4;
  #pragma unroll
  for (int k0 = 0; k0 < 64; k0 += 32){
    bh8 hb[4];
    #pragma unroll
    for (int nt = 0; nt < 4; nt++)
      hb[nt] = *(const bh8*)&h_t[wid*64 + nt*16 + col][k0 + quad*8];
    #pragma unroll
    for (int mt = 0; mt < 4; mt++){
      bh8 al = *(const bh8*)&pb[OFF_WL + (size_t)(mt*16 + col)*64 + k0 + quad*8];
      #pragma unroll
      for (int nt = 0; nt < 4; nt++)
        acc2[mt*4+nt] = __builtin_amdgcn_mfma_f32_16x16x32_bf16(al, hb[nt], acc2[mt*4+nt], 0, 0, 0);
    }
  }
  // ---- x += lk * (xs + 0.1*dx)
  float lk = fminf(fmaxf(leak[0], 0.001f), 1000.f);
  int ncol = l0 + wid*64;
  #pragma unroll
  for (int mt = 0; mt < 4; mt++){
    int f0 = mt*16 + quad*4;
    float bs0 = bf2f(pb[OFF_BS+f0]), bs1 = bf2f(pb[OFF_BS+f0+1]);
    float bs2 = bf2f(pb[OFF_BS+f0+2]), bs3 = bf2f(pb[OFF_BS+f0+3]);
    float bl0 = bf2f(pb[OFF_BL+f0]), bl1 = bf2f(pb[OFF_BL+f0+1]);
    float bl2 = bf2f(pb[OFF_BL+f0+2]), bl3 = bf2f(pb[OFF_BL+f0+3]);
    #pragma unroll
    for (int nt = 0; nt < 4; nt++){
      int s = ncol + nt*16 + col;
      f32x4 xs = acc_s[mt*4+nt], dx = acc2[mt*4+nt];
      float ov0 = xs[0] + bs0 + 0.1f*(dx[0] + bl0);
      float ov1 = xs[1] + bs1 + 0.1f*(dx[1] + bl1);
      float ov2 = xs[2] + bs2 + 0.1f*(dx[2] + bl2);
      float ov3 = xs[3] + bs3 + 0.1f*(dx[3] + bl3);
      size_t xi = ((size_t)b*C_ + f0)*L_ + s;
      x[xi]          += lk*ov0;
      x[xi + L_]     += lk*ov1;
      x[xi + 2*L_]   += lk*ov2;
      x[xi + 3*L_]   += lk*ov3;
    }
  }
}

// ---------------- conv_out1 (MFMA): t1bf = bf16(lrelu(conv3(leaky(x), out_w0)+out_b0))
__global__ __launch_bounds__(256) void k_conv_out1(const float* __restrict__ x,
    const float* __restrict__ w, const float* __restrict__ bias,
    unsigned short* __restrict__ t1bf){
  int b = blockIdx.x, l0 = blockIdx.y*128, tid = threadIdx.x;
  int wid = tid>>6, lane = tid&63, col = lane&15, quad = lane>>4;
  __shared__ __attribute__((aligned(16))) unsigned short xT[136][72];   // rows: l = l0-4+r
  __shared__ __attribute__((aligned(16))) unsigned short wA[3][64][72];
  for (int i = tid; i < 64*64; i += 256){
    int m = i >> 6, cin = i & 63;
    const float* s = w + (size_t)m*192 + cin*3;
    wA[0][m][cin] = f2bf(s[0]); wA[1][m][cin] = f2bf(s[1]); wA[2][m][cin] = f2bf(s[2]);
  }
  const float* xb = x + (size_t)b*C_*L_;
  for (int i = tid; i < 64*34; i += 256){
    int c = i / 34, g = i % 34;
    int lg = l0 - 4 + 4*g;
    if (lg >= 0 && lg + 3 < L_){
      float4 f = *(const float4*)&xb[(size_t)c*L_ + lg];
      xT[4*g  ][c] = f2bf(lrelu(f.x));
      xT[4*g+1][c] = f2bf(lrelu(f.y));
      xT[4*g+2][c] = f2bf(lrelu(f.z));
      xT[4*g+3][c] = f2bf(lrelu(f.w));
    } else {
      #pragma unroll
      for (int r2 = 0; r2 < 4; r2++){
        int l = lg + r2;
        float v = (l >= 0 && l < L_) ? xb[(size_t)c*L_ + l] : 0.f;
        xT[4*g + r2][c] = f2bf(lrelu(v));
      }
    }
  }
  __syncthreads();
  f32x4 z4 = {0.f,0.f,0.f,0.f};
  f32x4 acc[8];
  #pragma unroll
  for (int i = 0; i < 8; i++) acc[i] = z4;
  #pragma unroll
  for (int t = 0; t < 3; t++){
    #pragma unroll
    for (int k0 = 0; k0 < 64; k0 += 32){
      bh8 bfr[2];
      #pragma unroll
      for (int nt = 0; nt < 2; nt++)
        bfr[nt] = *(const bh8*)&xT[wid*32 + nt*16 + col + t + 3][k0 + quad*8];
      #pragma unroll
      for (int mt = 0; mt < 4; mt++){
        bh8 af = *(const bh8*)&wA[t][mt*16 + col][k0 + quad*8];
        #pragma unroll
        for (int nt = 0; nt < 2; nt++)
          acc[mt*2+nt] = __builtin_amdgcn_mfma_f32_16x16x32_bf16(af, bfr[nt], acc[mt*2+nt], 0,0,0);
      }
    }
  }
  #pragma unroll
  for (int mt = 0; mt < 4; mt++){
    int f0 = mt*16 + quad*4;
    float q0 = bias[f0], q1 = bias[f0+1], q2 = bias[f0+2], q3 = bias[f0+3];
    #pragma unroll
    for (int nt = 0; nt < 2; nt++){
      int l = l0 + wid*32 + nt*16 + col;
      f32x4 a = acc[mt*2+nt];
      uint2 o = { pk2(lrelu(a[0]+q0), lrelu(a[1]+q1)),
                  pk2(lrelu(a[2]+q2), lrelu(a[3]+q3)) };
      *(uint2*)&t1bf[((size_t)b*L_ + l)*64 + f0] = o;
    }
  }
}

// ---------------- conv_out2 (MFMA): x += 0.1*(conv3(leaky(t1), out_w1)+out_b1)
__global__ __launch_bounds__(256) void k_conv_out2(float* __restrict__ x,
    const unsigned short* __restrict__ t1bf, const float* __restrict__ w,
    const float* __restrict__ bias){
  int b = blockIdx.x, l0 = blockIdx.y*256, tid = threadIdx.x;
  int wid = tid>>6, lane = tid&63, col = lane&15, quad = lane>>4;
  __shared__ __attribute__((aligned(16))) unsigned short wA[3][64][72];
  for (int i = tid; i < 64*64; i += 256){
    int m = i >> 6, cin = i & 63;
    const float* s = w + (size_t)m*192 + cin*3;
    wA[0][m][cin] = f2bf(s[0]); wA[1][m][cin] = f2bf(s[1]); wA[2][m][cin] = f2bf(s[2]);
  }
  __syncthreads();
  f32x4 z4 = {0.f,0.f,0.f,0.f};
  f32x4 acc[16];
  #pragma unroll
  for (int i = 0; i < 16; i++) acc[i] = z4;
  bh8 zz8 = {0,0,0,0,0,0,0,0};
  #pragma unroll
  for (int t = 0; t < 3; t++){
    #pragma unroll
    for (int k0 = 0; k0 < 64; k0 += 32){
      bh8 bfr[4];
      #pragma unroll
      for (int nt = 0; nt < 4; nt++){
        int l = l0 + wid*64 + nt*16 + col + t - 1;
        bfr[nt] = (l >= 0 && l < L_)
          ? *(const bh8*)&t1bf[((size_t)b*L_ + l)*64 + k0 + quad*8] : zz8;
      }
      #pragma unroll
      for (int mt = 0; mt < 4; mt++){
        bh8 af = *(const bh8*)&wA[t][mt*16 + col][k0 + quad*8];
        #pragma unroll
        for (int nt = 0; nt < 4; nt++)
          acc[mt*4+nt] = __builtin_amdgcn_mfma_f32_16x16x32_bf16(af, bfr[nt], acc[mt*4+nt], 0,0,0);
      }
    }
  }
  #pragma unroll
  for (int mt = 0; mt < 4; mt++){
    int f0 = mt*16 + quad*4;
    float q0 = bias[f0], q1 = bias[f0+1], q2 = bias[f0+2], q3 = bias[f0+3];
    #pragma unroll
    for (int nt = 0; nt < 4; nt++){
      int l = l0 + wid*64 + nt*16 + col;
      f32x4 a = acc[mt*4+nt];
      size_t base = ((size_t)b*C_ + f0)*L_ + l;
      x[base]        += 0.1f*(a[0] + q0);
      x[base + L_]   += 0.1f*(a[1] + q1);
      x[base + 2*L_] += 0.1f*(a[2] + q2);
      x[base + 3*L_] += 0.1f*(a[3] + q3);
    }
  }
}

// ---------------- loss: cross-entropy vs argmax(codes)
__global__ __launch_bounds__(256) void k_loss(const float* __restrict__ x,
    const float* __restrict__ codes, float* __restrict__ out){
  int b = blockIdx.x;
  int l = blockIdx.y*256 + threadIdx.x;
  const float* xb = x + (size_t)b*C_*L_ + l;
  const float* cb = codes + (size_t)b*C_*L_ + l;
  float m = -1e30f, cm = -1e30f;
  int ci = 0;
  for (int c = 0; c < C_; c++){
    float xv = xb[(size_t)c*L_];
    m = fmaxf(m, xv);
    float cv = cb[(size_t)c*L_];
    if (cv > cm){ cm = cv; ci = c; }
  }
  float s = 0.f, vi = 0.f;
  for (int c = 0; c < C_; c++){
    float xv = xb[(size_t)c*L_];
    s += expf(xv - m);
    if (c == ci) vi = xv;
  }
  float lp = vi - m - logf(s);
  __shared__ float red[256];
  red[threadIdx.x] = -lp; __syncthreads();
  for (int sft = 128; sft; sft >>= 1){
    if (threadIdx.x < sft) red[threadIdx.x] += red[threadIdx.x + sft];
    __syncthreads();
  }
  if (threadIdx.x == 0) atomicAdd(out + B_*L_, red[0] * (1.0f/131072.0f));
}

// ---------------- lat head (MFMA): two 64x64 GEMMs per (b, 256-col tile) + lat2 reduce
__global__ __launch_bounds__(256) void k_lat(const float* __restrict__ x,
    const float* __restrict__ w10, const float* __restrict__ b10,
    const float* __restrict__ w11, const float* __restrict__ b11,
    const float* __restrict__ w20, const float* __restrict__ b20,
    const float* __restrict__ w21, const float* __restrict__ b21,
    const float* __restrict__ ws2, float* __restrict__ out){
  int b = blockIdx.x, l0 = blockIdx.y*256;
  int tid = threadIdx.x;
  int wid = tid >> 6, lane = tid & 63, col = lane & 15, quad = lane >> 4;
  __shared__ __attribute__((aligned(16))) unsigned short wA[2][64][72];
  __shared__ __attribute__((aligned(16))) unsigned short Bt[256][72];

  for (int i = tid; i < 1024; i += 256){
    int arr = i >> 9, rem = i & 511, row = rem >> 3, seg = rem & 7;
    const float* src = (arr ? w11 : w10) + (size_t)row*C_ + seg*8;
    *(bh8*)&wA[arr][row][seg*8] = cvt8(*(const float4*)src, *(const float4*)(src+4));
  }
  for (int i = tid; i < 4096; i += 256){
    int c = i >> 6, seg = i & 63;
    float4 v = *(const float4*)&x[((size_t)b*C_ + c)*L_ + l0 + seg*4];
    Bt[seg*4+0][c] = f2bf(lrelu(v.x));
    Bt[seg*4+1][c] = f2bf(lrelu(v.y));
    Bt[seg*4+2][c] = f2bf(lrelu(v.z));
    Bt[seg*4+3][c] = f2bf(lrelu(v.w));
  }
  __syncthreads();
  f32x4 z4 = {0.f,0.f,0.f,0.f};
  f32x4 acc1[16];
  #pragma unroll
  for (int i = 0; i < 16; i++) acc1[i] = z4;
  #pragma unroll
  for (int k0 = 0; k0 < 64; k0 += 32){
    bh8 bfr[4];
    #pragma unroll
    for (int nt = 0; nt < 4; nt++)
      bfr[nt] = *(const bh8*)&Bt[wid*64 + nt*16 + col][k0 + quad*8];
    #pragma unroll
    for (int mt = 0; mt < 4; mt++){
      bh8 af = *(const bh8*)&wA[0][mt*16 + col][k0 + quad*8];
      #pragma unroll
      for (int nt = 0; nt < 4; nt++)
        acc1[mt*4+nt] = __builtin_amdgcn_mfma_f32_16x16x32_bf16(af, bfr[nt], acc1[mt*4+nt], 0, 0, 0);
    }
  }
  #pragma unroll
  for (int mt = 0; mt < 4; mt++){
    int f0 = mt*16 + quad*4;
    f32x4 bv = *(const f32x4*)&b10[f0];
    #pragma unroll
    for (int nt = 0; nt < 4; nt++){
      int n = wid*64 + nt*16 + col;
      f32x4 a = acc1[mt*4+nt];
      uint2 o = { pk2(lrelu(a[0]+bv[0]), lrelu(a[1]+bv[1])),
                  pk2(lrelu(a[2]+bv[2]), lrelu(a[3]+bv[3])) };
      *(uint2*)&Bt[n][f0] = o;
    }
  }
  f32x4 acc2[16];
  #pragma unroll
  for (int i = 0; i < 16; i++) acc2[i] = z4;
  #pragma unroll
  for (int k0 = 0; k0 < 64; k0 += 32){
    bh8 bfr[4];
    #pragma unroll
    for (int nt = 0; nt < 4; nt++)
      bfr[nt] = *(const bh8*)&Bt[wid*64 + nt*16 + col][k0 + quad*8];
    #pragma unroll
    for (int mt = 0; mt < 4; mt++){
      bh8 af = *(const bh8*)&wA[1][mt*16 + col][k0 + quad*8];
      #pragma unroll
      for (int nt = 0; nt < 4; nt++)
        acc2[mt*4+nt] = __builtin_amdgcn_mfma_f32_16x16x32_bf16(af, bfr[nt], acc2[mt*4+nt], 0, 0, 0);
    }
  }
  float psA[4] = {0.f,0.f,0.f,0.f}, psB[4] = {0.f,0.f,0.f,0.f};
  #pragma unroll
  for (int mt = 0; mt < 4; mt++){
    int f0 = mt*16 + quad*4;
    f32x4 b11v = *(const f32x4*)&b11[f0];
    f32x4 wsv  = *(const f32x4*)&ws2[f0];
    f32x4 w20v = *(const f32x4*)&w20[f0];
    #pragma unroll
    for (int nt = 0; nt < 4; nt++){
      int lg = l0 + wid*64 + nt*16 + col;
      size_t base = ((size_t)b*C_ + f0)*L_ + lg;
      f32x4 a = acc2[mt*4+nt];
      #pragma unroll
      for (int r = 0; r < 4; r++){
        float xv = x[base + (size_t)r*L_];
        float lat = xv + 0.1f*(a[r] + b11v[r]);
        psA[nt] += wsv[r]*lat;
        psB[nt] += w20v[r]*lrelu(lat);
      }
    }
  }
  #pragma unroll
  for (int nt = 0; nt < 4; nt++){
    psA[nt] += __shfl_xor(psA[nt], 16); psA[nt] += __shfl_xor(psA[nt], 32);
    psB[nt] += __shfl_xor(psB[nt], 16); psB[nt] += __shfl_xor(psB[nt], 32);
  }
  if (quad == 0){
    float b20s = b20[0], w21s = w21[0], b21s = b21[0];
    #pragma unroll
    for (int nt = 0; nt < 4; nt++){
      float dx2 = w21s*lrelu(psB[nt] + b20s) + b21s;
      out[(size_t)b*L_ + l0 + wid*64 + nt*16 + col] = psA[nt] + 0.1f*dx2;
    }
  }
}

extern "C" void kernel_launch(void* const* d_in, const int* in_sizes, int n_in,
                              void* d_out, int out_size, void* d_ws, size_t ws_size,
                              hipStream_t stream) {
  (void)in_sizes; (void)n_in; (void)out_size; (void)ws_size;
  const float* codes   = (const float*)d_in[0];
  const int*   y       = (const int*)  d_in[1];
  const float* fc_w    = (const float*)d_in[2];
  const float* fc_b    = (const float*)d_in[3];
  const float* in_w0   = (const float*)d_in[4];
  const float* in_b0   = (const float*)d_in[5];
  const float* in_w1   = (const float*)d_in[6];
  const float* in_b1   = (const float*)d_in[7];
  const float* in_wsp  = (const float*)d_in[8];
  const float* leak    = (const float*)d_in[9];
  const float* hyper_w = (const float*)d_in[10];
  const float* hyper_b = (const float*)d_in[11];
  const float* out_w0  = (const float*)d_in[12];
  const float* out_b0  = (const float*)d_in[13];
  const float* out_w1  = (const float*)d_in[14];
  const float* out_b1  = (const float*)d_in[15];
  const float* l1_w0   = (const float*)d_in[16];
  const float* l1_b0   = (const float*)d_in[17];
  const float* l1_w1   = (const float*)d_in[18];
  const float* l1_b1   = (const float*)d_in[19];
  const float* l2_w0   = (const float*)d_in[20];
  const float* l2_b0   = (const float*)d_in[21];
  const float* l2_w1   = (const float*)d_in[22];
  const float* l2_b1   = (const float*)d_in[23];
  const float* l2_ws   = (const float*)d_in[24];
  float* out = (float*)d_out;

  char* ws = (char*)d_ws;
  unsigned short* p_bf = (unsigned short*)(ws);              // 18,972,672 B
  unsigned short* ybf  = (unsigned short*)(ws + 18972672);   // 131,072 B
  float* x             = (float*)(ws + 19103744);            // 33,554,432 B
  unsigned short* t1bf = (unsigned short*)(ws + 52658176);   // 16,777,216 B (outside loop)

  k_yemb<<<B_, 256, 0, stream>>>(fc_w, fc_b, y, ybf, out);
  k_hyper<<<PT_/64, 256, 0, stream>>>(hyper_w, hyper_b, ybf, p_bf);
  k_conv_in1<<<dim3(B_, 4), 256, 0, stream>>>(codes, in_w0, in_b0, t1bf);
  k_conv_in2<<<dim3(B_, 4), 256, 0, stream>>>(codes, in_wsp, in_w1, in_b1, t1bf, x);
  for (int it = 0; it < 8; ++it){
    k_iter<<<dim3(B_, 2), 256, 0, stream>>>(x, p_bf, leak);
  }
  k_conv_out1<<<dim3(B_, 4), 256, 0, stream>>>(x, out_w0, out_b0, t1bf);
  k_conv_out2<<<dim3(B_, 2), 256, 0, stream>>>(x, t1bf, out_w1, out_b1);
  k_loss<<<dim3(B_, 2), 256, 0, stream>>>(x, codes, out);
  k_lat<<<dim3(B_, 2), 256, 0, stream>>>(x, l1_w0, l1_b0, l1_w1, l1_b1,
                                         l2_w0, l2_b0, l2_w1, l2_b1, l2_ws, out);
}

// Round 7
// 926.351 us; speedup vs baseline: 1.1487x; 1.1487x over previous
//
#include <hip/hip_runtime.h>

#define B_ 256
#define C_ 64
#define L_ 512
#define CIN_ 82
#define NFREQ_ 9
#define EMB_ 256
#define NLAB_ 10
#define PT_ 37056
#define OFF_BH 16384
#define OFF_WL 16448
#define OFF_BL 20544
#define OFF_WS 20608
#define OFF_BS 36992
#define PI_F 3.14159265358979323846f

typedef short bh8 __attribute__((ext_vector_type(8)));   // 8 bf16 (raw bits)
typedef float f32x4 __attribute__((ext_vector_type(4)));

__device__ inline float lrelu(float v){ return v > 0.f ? v : 0.2f*v; }

__device__ inline unsigned short f2bf(float f){
  unsigned u = __float_as_uint(f);
  u += 0x7FFFu + ((u >> 16) & 1u);      // RNE
  return (unsigned short)(u >> 16);
}
__device__ inline float bf2f(unsigned short u){
  return __uint_as_float((unsigned)u << 16);
}
__device__ inline unsigned pk2(float a, float b){
  return (unsigned)f2bf(a) | ((unsigned)f2bf(b) << 16);
}
__device__ inline bh8 cvt8(float4 a, float4 b){
  bh8 r;
  r[0]=(short)f2bf(a.x); r[1]=(short)f2bf(a.y); r[2]=(short)f2bf(a.z); r[3]=(short)f2bf(a.w);
  r[4]=(short)f2bf(b.x); r[5]=(short)f2bf(b.y); r[6]=(short)f2bf(b.z); r[7]=(short)f2bf(b.w);
  return r;
}
// 16B fragment via four 4B loads (4B-aligned LDS rows)
__device__ inline bh8 ld16_4(const unsigned short* p){
  union { unsigned u[4]; bh8 v; } t;
  t.u[0]=*(const unsigned*)p;     t.u[1]=*(const unsigned*)(p+2);
  t.u[2]=*(const unsigned*)(p+4); t.u[3]=*(const unsigned*)(p+6);
  return t.v;
}
// 16B fragment via two 8B loads (8B-aligned LDS rows)
__device__ inline bh8 ld8(const unsigned short* p){
  union { uint2 u[2]; bh8 v; } t;
  t.u[0] = *(const uint2*)p; t.u[1] = *(const uint2*)(p+4);
  return t.v;
}

// k-permutation for wh/ws sections: orig i = br*64+c  ->  k = 4c+br
__device__ inline int perm_j(int j){
  if (j < OFF_BH){ int m = j >> 8, i = j & 255; return (m << 8) + ((i & 63) << 2) + (i >> 6); }
  if (j >= OFF_WS && j < OFF_BS){
    int jj = j - OFF_WS; int m = jj >> 8, i = jj & 255;
    return OFF_WS + (m << 8) + ((i & 63) << 2) + (i >> 6);
  }
  return j;
}

// ---------------- yemb: normalize(fc_w[:,y]+fc_b) -> bf16 [b][e]; zero loss slot
__global__ __launch_bounds__(256) void k_yemb(const float* __restrict__ fc_w,
    const float* __restrict__ fc_b, const int* __restrict__ y,
    unsigned short* __restrict__ ybf, float* __restrict__ out){
  int b = blockIdx.x, e = threadIdx.x;
  int lab = y[b];
  float v = fc_w[e*NLAB_ + lab] + fc_b[e];
  __shared__ float red[256];
  red[e] = v*v; __syncthreads();
  for (int s = 128; s; s >>= 1){ if (e < s) red[e] += red[e+s]; __syncthreads(); }
  float nrm = fmaxf(sqrtf(red[0]), 1e-12f);
  ybf[(size_t)b*EMB_ + e] = f2bf(v / nrm);
  if (b == 0 && e == 0) out[B_*L_] = 0.f;
}

// ---------------- hyper (MFMA): p_bf[b][perm(j)] = bf16(yemb[b][:] . hw[j][:] + hb[j])
__global__ __launch_bounds__(256) void k_hyper(const float* __restrict__ hw,
    const float* __restrict__ hb, const unsigned short* __restrict__ ybf,
    unsigned short* __restrict__ p_bf){
  int tid = threadIdx.x;
  int wid = tid >> 6, lane = tid & 63, col = lane & 15, quad = lane >> 4;
  int j = blockIdx.x*64 + wid*16 + col;
  f32x4 acc[16];
  f32x4 z4 = {0.f,0.f,0.f,0.f};
  #pragma unroll
  for (int i = 0; i < 16; i++) acc[i] = z4;
  for (int k0 = 0; k0 < 256; k0 += 32){
    const float* hp = hw + (size_t)j*EMB_ + k0 + quad*8;
    bh8 bf = cvt8(*(const float4*)hp, *(const float4*)(hp+4));
    #pragma unroll
    for (int mt = 0; mt < 16; mt++){
      bh8 af = *(const bh8*)&ybf[(size_t)(mt*16 + col)*EMB_ + k0 + quad*8];
      acc[mt] = __builtin_amdgcn_mfma_f32_16x16x32_bf16(af, bf, acc[mt], 0, 0, 0);
    }
  }
  float hbv = hb[j];
  int jd = perm_j(j);
  #pragma unroll
  for (int mt = 0; mt < 16; mt++){
    int b0 = mt*16 + quad*4;
    #pragma unroll
    for (int r = 0; r < 4; r++)
      p_bf[(size_t)(b0 + r)*PT_ + jd] = f2bf(acc[mt][r] + hbv);
  }
}

// positional encoding value (raw)
__device__ inline float pe_raw(int fi, int l){
  if (fi < NFREQ_) return __sinf(PI_F / (float)(1 << fi) * (float)l);
  return __cosf(PI_F / (float)(1 << (fi - NFREQ_)) * (float)l);
}

// ---------------- conv_in1 (MFMA): t1bf[b][l][m] = bf16(lrelu(conv3(leaky(xcat), in_w0)+in_b0))
// grid (B,4). R5 structure; LDS stride 104 (208B = 13x16B: 16B-aligned b128, 2-way banks).
__global__ __launch_bounds__(256) void k_conv_in1(const float* __restrict__ codes,
    const float* __restrict__ w0, const float* __restrict__ b0,
    unsigned short* __restrict__ t1bf){
  int b = blockIdx.x, l0 = blockIdx.y*128, tid = threadIdx.x;
  int wid = tid>>6, lane = tid&63, col = lane&15, quad = lane>>4;
  __shared__ __attribute__((aligned(16))) unsigned short xT[136][104];     // rows: l = l0-4+r
  __shared__ __attribute__((aligned(16))) unsigned short wA[3][64][104];
  for (int i = tid; i < 64*96; i += 256){
    int m = i / 96, cin = i % 96;
    if (cin < CIN_){
      const float* s = w0 + (size_t)m*(CIN_*3) + cin*3;
      wA[0][m][cin] = f2bf(s[0]); wA[1][m][cin] = f2bf(s[1]); wA[2][m][cin] = f2bf(s[2]);
    } else { wA[0][m][cin] = 0; wA[1][m][cin] = 0; wA[2][m][cin] = 0; }
  }
  const float* cb = codes + (size_t)b*C_*L_;
  for (int i = tid; i < 96*34; i += 256){
    int c = i / 34, g = i % 34;
    int lg = l0 - 4 + 4*g;
    #pragma unroll
    for (int r2 = 0; r2 < 4; r2++){
      int l = lg + r2;
      float xv = 0.f;
      if (l >= 0 && l < L_){
        if (c < C_) xv = cb[(size_t)c*L_ + l];
        else if (c < CIN_) xv = pe_raw(c - C_, l);
      }
      xT[4*g + r2][c] = f2bf(lrelu(xv));
    }
  }
  __syncthreads();
  f32x4 z4 = {0.f,0.f,0.f,0.f};
  f32x4 acc[8];
  #pragma unroll
  for (int i = 0; i < 8; i++) acc[i] = z4;
  #pragma unroll
  for (int t = 0; t < 3; t++){
    #pragma unroll
    for (int k0 = 0; k0 < 96; k0 += 32){
      bh8 bfr[2];
      #pragma unroll
      for (int nt = 0; nt < 2; nt++)
        bfr[nt] = *(const bh8*)&xT[wid*32 + nt*16 + col + t + 3][k0 + quad*8];
      #pragma unroll
      for (int mt = 0; mt < 4; mt++){
        bh8 af = *(const bh8*)&wA[t][mt*16 + col][k0 + quad*8];
        #pragma unroll
        for (int nt = 0; nt < 2; nt++)
          acc[mt*2+nt] = __builtin_amdgcn_mfma_f32_16x16x32_bf16(af, bfr[nt], acc[mt*2+nt], 0,0,0);
      }
    }
  }
  #pragma unroll
  for (int mt = 0; mt < 4; mt++){
    int f0 = mt*16 + quad*4;
    float q0 = b0[f0], q1 = b0[f0+1], q2 = b0[f0+2], q3 = b0[f0+3];
    #pragma unroll
    for (int nt = 0; nt < 2; nt++){
      int l = l0 + wid*32 + nt*16 + col;
      f32x4 a = acc[mt*2+nt];
      uint2 o = { pk2(lrelu(a[0]+q0), lrelu(a[1]+q1)),
                  pk2(lrelu(a[2]+q2), lrelu(a[3]+q3)) };
      *(uint2*)&t1bf[((size_t)b*L_ + l)*64 + f0] = o;
    }
  }
}

// ---------------- conv_in2 (MFMA): x = conv1x1(xcat, in_ws) + 0.1*(conv3(leaky(t1), in_w1)+in_b1)
// grid (B,4). Strides 104/104/72 (all 16B-aligned b128, 2-way banks).
__global__ __launch_bounds__(256) void k_conv_in2(const float* __restrict__ codes,
    const float* __restrict__ wsp, const float* __restrict__ w1, const float* __restrict__ b1,
    const unsigned short* __restrict__ t1bf, float* __restrict__ x){
  int b = blockIdx.x, l0 = blockIdx.y*128, tid = threadIdx.x;
  int wid = tid>>6, lane = tid&63, col = lane&15, quad = lane>>4;
  __shared__ __attribute__((aligned(16))) unsigned short xT[128][104];   // raw xcat
  __shared__ __attribute__((aligned(16))) unsigned short wsA[64][104];
  __shared__ __attribute__((aligned(16))) unsigned short w1A[3][64][72];
  for (int i = tid; i < 64*96; i += 256){
    int m = i / 96, cin = i % 96;
    wsA[m][cin] = (cin < CIN_) ? f2bf(wsp[(size_t)m*CIN_ + cin]) : (unsigned short)0;
  }
  for (int i = tid; i < 64*64; i += 256){
    int m = i >> 6, cin = i & 63;
    const float* s = w1 + (size_t)m*192 + cin*3;
    w1A[0][m][cin] = f2bf(s[0]); w1A[1][m][cin] = f2bf(s[1]); w1A[2][m][cin] = f2bf(s[2]);
  }
  const float* cb = codes + (size_t)b*C_*L_;
  for (int i = tid; i < 96*32; i += 256){
    int c = i / 32, g = i % 32;
    int lg = l0 + 4*g;
    #pragma unroll
    for (int r2 = 0; r2 < 4; r2++){
      int l = lg + r2;
      float xv;
      if (c < C_) xv = cb[(size_t)c*L_ + l];
      else if (c < CIN_) xv = pe_raw(c - C_, l);
      else xv = 0.f;
      xT[4*g + r2][c] = f2bf(xv);
    }
  }
  __syncthreads();
  f32x4 z4 = {0.f,0.f,0.f,0.f};
  f32x4 accS[8], accD[8];
  #pragma unroll
  for (int i = 0; i < 8; i++){ accS[i] = z4; accD[i] = z4; }
  #pragma unroll
  for (int k0 = 0; k0 < 96; k0 += 32){
    bh8 bfr[2];
    #pragma unroll
    for (int nt = 0; nt < 2; nt++)
      bfr[nt] = *(const bh8*)&xT[wid*32 + nt*16 + col][k0 + quad*8];
    #pragma unroll
    for (int mt = 0; mt < 4; mt++){
      bh8 af = *(const bh8*)&wsA[mt*16 + col][k0 + quad*8];
      #pragma unroll
      for (int nt = 0; nt < 2; nt++)
        accS[mt*2+nt] = __builtin_amdgcn_mfma_f32_16x16x32_bf16(af, bfr[nt], accS[mt*2+nt], 0,0,0);
    }
  }
  bh8 zz8 = {0,0,0,0,0,0,0,0};
  #pragma unroll
  for (int t = 0; t < 3; t++){
    #pragma unroll
    for (int k0 = 0; k0 < 64; k0 += 32){
      bh8 bfr[2];
      #pragma unroll
      for (int nt = 0; nt < 2; nt++){
        int l = l0 + wid*32 + nt*16 + col + t - 1;
        bfr[nt] = (l >= 0 && l < L_)
          ? *(const bh8*)&t1bf[((size_t)b*L_ + l)*64 + k0 + quad*8] : zz8;
      }
      #pragma unroll
      for (int mt = 0; mt < 4; mt++){
        bh8 af = *(const bh8*)&w1A[t][mt*16 + col][k0 + quad*8];
        #pragma unroll
        for (int nt = 0; nt < 2; nt++)
          accD[mt*2+nt] = __builtin_amdgcn_mfma_f32_16x16x32_bf16(af, bfr[nt], accD[mt*2+nt], 0,0,0);
      }
    }
  }
  #pragma unroll
  for (int mt = 0; mt < 4; mt++){
    int f0 = mt*16 + quad*4;
    float q0 = b1[f0], q1 = b1[f0+1], q2 = b1[f0+2], q3 = b1[f0+3];
    #pragma unroll
    for (int nt = 0; nt < 2; nt++){
      int l = l0 + wid*32 + nt*16 + col;
      f32x4 s = accS[mt*2+nt], d = accD[mt*2+nt];
      size_t base = ((size_t)b*C_ + f0)*L_ + l;
      x[base]        = s[0] + 0.1f*(d[0] + q0);
      x[base + L_]   = s[1] + 0.1f*(d[1] + q1);
      x[base + 2*L_] = s[2] + 0.1f*(d[2] + q2);
      x[base + 3*L_] = s[3] + 0.1f*(d[3] + q3);
    }
  }
}

// ---------------- k_iter: fused inst-norm + sin-sobel + hypernet GEMMs + x update
// ONE block per sample: 512 threads (8 waves); each channel's sobel computed exactly once.
__global__ __launch_bounds__(512, 2) void k_iter(float* __restrict__ x,
    const unsigned short* __restrict__ p_bf, const float* __restrict__ leak){
  int b = blockIdx.x, tid = threadIdx.x;
  int wid = tid >> 6, lane = tid & 63, col = lane & 15, quad = lane >> 4;
  const unsigned short* pb = p_bf + (size_t)b*PT_;
  float* xb = x + (size_t)b*C_*L_;

  __shared__ __attribute__((aligned(16))) unsigned short h_t[512][68];  // 69632 B
  unsigned short (*fch)[42] = (unsigned short (*)[42])&h_t[0][0];       // alias, 43008 B
  __shared__ float sm[64], sr[64];

  // ---- stats: 8 waves x 8 channels, full-row wave reduction
  #pragma unroll
  for (int t = 0; t < 8; t++){
    int c = t*8 + wid;
    const float* xr = xb + (size_t)c*L_ + lane*8;
    float4 v0 = *(const float4*)xr, v1 = *(const float4*)(xr+4);
    float s1 = v0.x+v0.y+v0.z+v0.w + v1.x+v1.y+v1.z+v1.w;
    float s2 = v0.x*v0.x+v0.y*v0.y+v0.z*v0.z+v0.w*v0.w
             + v1.x*v1.x+v1.y*v1.y+v1.z*v1.z+v1.w*v1.w;
    #pragma unroll
    for (int m = 32; m; m >>= 1){ s1 += __shfl_xor(s1, m); s2 += __shfl_xor(s2, m); }
    if (lane == 0){
      float mean = s1 * (1.f/512.f);
      sm[c] = mean;
      sr[c] = rsqrtf(s2*(1.f/512.f) - mean*mean + 1e-5f);
    }
  }
  __syncthreads();

  f32x4 zz4 = {0.f,0.f,0.f,0.f};
  f32x4 acc_h[16], acc_s[16];
  #pragma unroll
  for (int i = 0; i < 16; i++){ acc_h[i] = zz4; acc_s[i] = zz4; }

  int yy = lane & 7;
  float wm = (yy > 0) ? 1.f : 0.f, wp = (yy < 7) ? 1.f : 0.f;
  float qm = (lane >= 8) ? 1.f : 0.f, qp = (lane < 56) ? 1.f : 0.f;

  for (int ch = 0; ch < 8; ch++){
    // ---- produce: each wave one channel, full 512-row, once
    int c = ch*8 + wid;
    {
      const float* xr = xb + (size_t)c*L_ + lane*8;
      float4 v0 = *(const float4*)xr, v1 = *(const float4*)(xr+4);
      float r8[8] = { v0.x, v0.y, v0.z, v0.w, v1.x, v1.y, v1.z, v1.w };
      float mean = sm[c], rstd = sr[c];
      float xn[8];
      #pragma unroll
      for (int i = 0; i < 8; i++) xn[i] = (r8[i] - mean) * rstd;
      float A[8], Bv[8];
      A[0] = 2.f*xn[0] + xn[1];  Bv[0] = xn[1];
      #pragma unroll
      for (int i = 1; i < 7; i++){ A[i] = xn[i-1] + 2.f*xn[i] + xn[i+1]; Bv[i] = xn[i+1] - xn[i-1]; }
      A[7] = xn[6] + 2.f*xn[7];  Bv[7] = -xn[6];
      float Cv[8], Dv[8], Ev[8];
      #pragma unroll
      for (int i = 0; i < 8; i++){
        float am = __shfl_up(A[i], 1)*wm,  ap = __shfl_down(A[i], 1)*wp;
        float bm = __shfl_up(Bv[i], 1)*wm, bp = __shfl_down(Bv[i], 1)*wp;
        Cv[i] = am + 2.f*A[i] + ap;
        Dv[i] = ap - am;
        Ev[i] = bm + 2.f*Bv[i] + bp;
      }
      uint2 val[8];
      #pragma unroll
      for (int i = 0; i < 8; i++){
        float cm = __shfl_up(Cv[i], 8)*qm, cp = __shfl_down(Cv[i], 8)*qp;
        float dm = __shfl_up(Dv[i], 8)*qm, dp = __shfl_down(Dv[i], 8)*qp;
        float em = __shfl_up(Ev[i], 8)*qm, ep = __shfl_down(Ev[i], 8)*qp;
        float G0 = cp - cm;
        float G1 = dm + 2.f*Dv[i] + dp;
        float G2 = em + 2.f*Ev[i] + ep;
        val[i].x = pk2(xn[i], __sinf(G0));
        val[i].y = pk2(__sinf(G1), __sinf(G2));
      }
      int lrow = lane*8;
      #pragma unroll
      for (int j = 0; j < 8; j++){
        int i = (j + yy) & 7;      // stagger to spread LDS banks
        unsigned short* dst = &fch[lrow + i][wid*4];
        *(unsigned*)dst       = val[i].x;
        *(unsigned*)(dst + 2) = val[i].y;
      }
    }
    __syncthreads();
    // ---- consume: one K=32 MFMA step over this wave's 64 n-cols
    bh8 bfr[4];
    #pragma unroll
    for (int nt = 0; nt < 4; nt++)
      bfr[nt] = ld16_4(&fch[wid*64 + nt*16 + col][quad*8]);
    #pragma unroll
    for (int mt = 0; mt < 4; mt++){
      int m = mt*16 + col;
      bh8 ah = *(const bh8*)&pb[(size_t)m*256 + ch*32 + quad*8];
      bh8 aw = *(const bh8*)&pb[OFF_WS + (size_t)m*256 + ch*32 + quad*8];
      #pragma unroll
      for (int nt = 0; nt < 4; nt++){
        acc_h[mt*4+nt] = __builtin_amdgcn_mfma_f32_16x16x32_bf16(ah, bfr[nt], acc_h[mt*4+nt], 0, 0, 0);
        acc_s[mt*4+nt] = __builtin_amdgcn_mfma_f32_16x16x32_bf16(aw, bfr[nt], acc_s[mt*4+nt], 0, 0, 0);
      }
    }
    __syncthreads();   // protects fch before next produce (and before h_t alias use)
  }

  // ---- h = leaky(acc_h + bh) -> h_t  (fch dead; alias safe after barrier above)
  #pragma unroll
  for (int mt = 0; mt < 4; mt++){
    int f0 = mt*16 + quad*4;
    float bh0 = bf2f(pb[OFF_BH+f0]), bh1 = bf2f(pb[OFF_BH+f0+1]);
    float bh2 = bf2f(pb[OFF_BH+f0+2]), bh3 = bf2f(pb[OFF_BH+f0+3]);
    #pragma unroll
    for (int nt = 0; nt < 4; nt++){
      int n = wid*64 + nt*16 + col;
      f32x4 a = acc_h[mt*4+nt];
      uint2 o = { pk2(lrelu(a[0]+bh0), lrelu(a[1]+bh1)),
                  pk2(lrelu(a[2]+bh2), lrelu(a[3]+bh3)) };
      *(uint2*)&h_t[n][f0] = o;
    }
  }
  __syncthreads();
  // ---- phase 2: acc2 = wl @ h
  f32x4 acc2[16];
  #pragma unroll
  for (int i = 0; i < 16; i++) acc2[i] = zz4;
  #pragma unroll
  for (int k0 = 0; k0 < 64; k0 += 32){
    bh8 hb[4];
    #pragma unroll
    for (int nt = 0; nt < 4; nt++)
      hb[nt] = ld8(&h_t[wid*64 + nt*16 + col][k0 + quad*8]);
    #pragma unroll
    for (int mt = 0; mt < 4; mt++){
      bh8 al = *(const bh8*)&pb[OFF_WL + (size_t)(mt*16 + col)*64 + k0 + quad*8];
      #pragma unroll
      for (int nt = 0; nt < 4; nt++)
        acc2[mt*4+nt] = __builtin_amdgcn_mfma_f32_16x16x32_bf16(al, hb[nt], acc2[mt*4+nt], 0, 0, 0);
    }
  }
  // ---- x += lk * (xs + 0.1*dx)
  float lk = fminf(fmaxf(leak[0], 0.001f), 1000.f);
  int ncol = wid*64;
  #pragma unroll
  for (int mt = 0; mt < 4; mt++){
    int f0 = mt*16 + quad*4;
    float bs0 = bf2f(pb[OFF_BS+f0]), bs1 = bf2f(pb[OFF_BS+f0+1]);
    float bs2 = bf2f(pb[OFF_BS+f0+2]), bs3 = bf2f(pb[OFF_BS+f0+3]);
    float bl0 = bf2f(pb[OFF_BL+f0]), bl1 = bf2f(pb[OFF_BL+f0+1]);
    float bl2 = bf2f(pb[OFF_BL+f0+2]), bl3 = bf2f(pb[OFF_BL+f0+3]);
    #pragma unroll
    for (int nt = 0; nt < 4; nt++){
      int s = ncol + nt*16 + col;
      f32x4 xs = acc_s[mt*4+nt], dx = acc2[mt*4+nt];
      float ov0 = xs[0] + bs0 + 0.1f*(dx[0] + bl0);
      float ov1 = xs[1] + bs1 + 0.1f*(dx[1] + bl1);
      float ov2 = xs[2] + bs2 + 0.1f*(dx[2] + bl2);
      float ov3 = xs[3] + bs3 + 0.1f*(dx[3] + bl3);
      size_t xi = ((size_t)b*C_ + f0)*L_ + s;
      x[xi]          += lk*ov0;
      x[xi + L_]     += lk*ov1;
      x[xi + 2*L_]   += lk*ov2;
      x[xi + 3*L_]   += lk*ov3;
    }
  }
}

// ---------------- conv_out1 (MFMA): t1bf = bf16(lrelu(conv3(leaky(x), out_w0)+out_b0))
__global__ __launch_bounds__(256) void k_conv_out1(const float* __restrict__ x,
    const float* __restrict__ w, const float* __restrict__ bias,
    unsigned short* __restrict__ t1bf){
  int b = blockIdx.x, l0 = blockIdx.y*128, tid = threadIdx.x;
  int wid = tid>>6, lane = tid&63, col = lane&15, quad = lane>>4;
  __shared__ __attribute__((aligned(16))) unsigned short xT[136][72];   // rows: l = l0-4+r
  __shared__ __attribute__((aligned(16))) unsigned short wA[3][64][72];
  for (int i = tid; i < 64*64; i += 256){
    int m = i >> 6, cin = i & 63;
    const float* s = w + (size_t)m*192 + cin*3;
    wA[0][m][cin] = f2bf(s[0]); wA[1][m][cin] = f2bf(s[1]); wA[2][m][cin] = f2bf(s[2]);
  }
  const float* xb = x + (size_t)b*C_*L_;
  for (int i = tid; i < 64*34; i += 256){
    int c = i / 34, g = i % 34;
    int lg = l0 - 4 + 4*g;
    if (lg >= 0 && lg + 3 < L_){
      float4 f = *(const float4*)&xb[(size_t)c*L_ + lg];
      xT[4*g  ][c] = f2bf(lrelu(f.x));
      xT[4*g+1][c] = f2bf(lrelu(f.y));
      xT[4*g+2][c] = f2bf(lrelu(f.z));
      xT[4*g+3][c] = f2bf(lrelu(f.w));
    } else {
      #pragma unroll
      for (int r2 = 0; r2 < 4; r2++){
        int l = lg + r2;
        float v = (l >= 0 && l < L_) ? xb[(size_t)c*L_ + l] : 0.f;
        xT[4*g + r2][c] = f2bf(lrelu(v));
      }
    }
  }
  __syncthreads();
  f32x4 z4 = {0.f,0.f,0.f,0.f};
  f32x4 acc[8];
  #pragma unroll
  for (int i = 0; i < 8; i++) acc[i] = z4;
  #pragma unroll
  for (int t = 0; t < 3; t++){
    #pragma unroll
    for (int k0 = 0; k0 < 64; k0 += 32){
      bh8 bfr[2];
      #pragma unroll
      for (int nt = 0; nt < 2; nt++)
        bfr[nt] = *(const bh8*)&xT[wid*32 + nt*16 + col + t + 3][k0 + quad*8];
      #pragma unroll
      for (int mt = 0; mt < 4; mt++){
        bh8 af = *(const bh8*)&wA[t][mt*16 + col][k0 + quad*8];
        #pragma unroll
        for (int nt = 0; nt < 2; nt++)
          acc[mt*2+nt] = __builtin_amdgcn_mfma_f32_16x16x32_bf16(af, bfr[nt], acc[mt*2+nt], 0,0,0);
      }
    }
  }
  #pragma unroll
  for (int mt = 0; mt < 4; mt++){
    int f0 = mt*16 + quad*4;
    float q0 = bias[f0], q1 = bias[f0+1], q2 = bias[f0+2], q3 = bias[f0+3];
    #pragma unroll
    for (int nt = 0; nt < 2; nt++){
      int l = l0 + wid*32 + nt*16 + col;
      f32x4 a = acc[mt*2+nt];
      uint2 o = { pk2(lrelu(a[0]+q0), lrelu(a[1]+q1)),
                  pk2(lrelu(a[2]+q2), lrelu(a[3]+q3)) };
      *(uint2*)&t1bf[((size_t)b*L_ + l)*64 + f0] = o;
    }
  }
}

// ---------------- conv_out2 (MFMA): x += 0.1*(conv3(leaky(t1), out_w1)+out_b1)
__global__ __launch_bounds__(256) void k_conv_out2(float* __restrict__ x,
    const unsigned short* __restrict__ t1bf, const float* __restrict__ w,
    const float* __restrict__ bias){
  int b = blockIdx.x, l0 = blockIdx.y*256, tid = threadIdx.x;
  int wid = tid>>6, lane = tid&63, col = lane&15, quad = lane>>4;
  __shared__ __attribute__((aligned(16))) unsigned short wA[3][64][72];
  for (int i = tid; i < 64*64; i += 256){
    int m = i >> 6, cin = i & 63;
    const float* s = w + (size_t)m*192 + cin*3;
    wA[0][m][cin] = f2bf(s[0]); wA[1][m][cin] = f2bf(s[1]); wA[2][m][cin] = f2bf(s[2]);
  }
  __syncthreads();
  f32x4 z4 = {0.f,0.f,0.f,0.f};
  f32x4 acc[16];
  #pragma unroll
  for (int i = 0; i < 16; i++) acc[i] = z4;
  bh8 zz8 = {0,0,0,0,0,0,0,0};
  #pragma unroll
  for (int t = 0; t < 3; t++){
    #pragma unroll
    for (int k0 = 0; k0 < 64; k0 += 32){
      bh8 bfr[4];
      #pragma unroll
      for (int nt = 0; nt < 4; nt++){
        int l = l0 + wid*64 + nt*16 + col + t - 1;
        bfr[nt] = (l >= 0 && l < L_)
          ? *(const bh8*)&t1bf[((size_t)b*L_ + l)*64 + k0 + quad*8] : zz8;
      }
      #pragma unroll
      for (int mt = 0; mt < 4; mt++){
        bh8 af = *(const bh8*)&wA[t][mt*16 + col][k0 + quad*8];
        #pragma unroll
        for (int nt = 0; nt < 4; nt++)
          acc[mt*4+nt] = __builtin_amdgcn_mfma_f32_16x16x32_bf16(af, bfr[nt], acc[mt*4+nt], 0,0,0);
      }
    }
  }
  #pragma unroll
  for (int mt = 0; mt < 4; mt++){
    int f0 = mt*16 + quad*4;
    float q0 = bias[f0], q1 = bias[f0+1], q2 = bias[f0+2], q3 = bias[f0+3];
    #pragma unroll
    for (int nt = 0; nt < 4; nt++){
      int l = l0 + wid*64 + nt*16 + col;
      f32x4 a = acc[mt*4+nt];
      size_t base = ((size_t)b*C_ + f0)*L_ + l;
      x[base]        += 0.1f*(a[0] + q0);
      x[base + L_]   += 0.1f*(a[1] + q1);
      x[base + 2*L_] += 0.1f*(a[2] + q2);
      x[base + 3*L_] += 0.1f*(a[3] + q3);
    }
  }
}

// ---------------- loss: cross-entropy vs argmax(codes)
__global__ __launch_bounds__(256) void k_loss(const float* __restrict__ x,
    const float* __restrict__ codes, float* __restrict__ out){
  int b = blockIdx.x;
  int l = blockIdx.y*256 + threadIdx.x;
  const float* xb = x + (size_t)b*C_*L_ + l;
  const float* cb = codes + (size_t)b*C_*L_ + l;
  float m = -1e30f, cm = -1e30f;
  int ci = 0;
  for (int c = 0; c < C_; c++){
    float xv = xb[(size_t)c*L_];
    m = fmaxf(m, xv);
    float cv = cb[(size_t)c*L_];
    if (cv > cm){ cm = cv; ci = c; }
  }
  float s = 0.f, vi = 0.f;
  for (int c = 0; c < C_; c++){
    float xv = xb[(size_t)c*L_];
    s += expf(xv - m);
    if (c == ci) vi = xv;
  }
  float lp = vi - m - logf(s);
  __shared__ float red[256];
  red[threadIdx.x] = -lp; __syncthreads();
  for (int sft = 128; sft; sft >>= 1){
    if (threadIdx.x < sft) red[threadIdx.x] += red[threadIdx.x + sft];
    __syncthreads();
  }
  if (threadIdx.x == 0) atomicAdd(out + B_*L_, red[0] * (1.0f/131072.0f));
}

// ---------------- lat head (MFMA): two 64x64 GEMMs per (b, 256-col tile) + lat2 reduce
__global__ __launch_bounds__(256) void k_lat(const float* __restrict__ x,
    const float* __restrict__ w10, const float* __restrict__ b10,
    const float* __restrict__ w11, const float* __restrict__ b11,
    const float* __restrict__ w20, const float* __restrict__ b20,
    const float* __restrict__ w21, const float* __restrict__ b21,
    const float* __restrict__ ws2, float* __restrict__ out){
  int b = blockIdx.x, l0 = blockIdx.y*256;
  int tid = threadIdx.x;
  int wid = tid >> 6, lane = tid & 63, col = lane & 15, quad = lane >> 4;
  __shared__ __attribute__((aligned(16))) unsigned short wA[2][64][72];
  __shared__ __attribute__((aligned(16))) unsigned short Bt[256][72];

  for (int i = tid; i < 1024; i += 256){
    int arr = i >> 9, rem = i & 511, row = rem >> 3, seg = rem & 7;
    const float* src = (arr ? w11 : w10) + (size_t)row*C_ + seg*8;
    *(bh8*)&wA[arr][row][seg*8] = cvt8(*(const float4*)src, *(const float4*)(src+4));
  }
  for (int i = tid; i < 4096; i += 256){
    int c = i >> 6, seg = i & 63;
    float4 v = *(const float4*)&x[((size_t)b*C_ + c)*L_ + l0 + seg*4];
    Bt[seg*4+0][c] = f2bf(lrelu(v.x));
    Bt[seg*4+1][c] = f2bf(lrelu(v.y));
    Bt[seg*4+2][c] = f2bf(lrelu(v.z));
    Bt[seg*4+3][c] = f2bf(lrelu(v.w));
  }
  __syncthreads();
  f32x4 z4 = {0.f,0.f,0.f,0.f};
  f32x4 acc1[16];
  #pragma unroll
  for (int i = 0; i < 16; i++) acc1[i] = z4;
  #pragma unroll
  for (int k0 = 0; k0 < 64; k0 += 32){
    bh8 bfr[4];
    #pragma unroll
    for (int nt = 0; nt < 4; nt++)
      bfr[nt] = *(const bh8*)&Bt[wid*64 + nt*16 + col][k0 + quad*8];
    #pragma unroll
    for (int mt = 0; mt < 4; mt++){
      bh8 af = *(const bh8*)&wA[0][mt*16 + col][k0 + quad*8];
      #pragma unroll
      for (int nt = 0; nt < 4; nt++)
        acc1[mt*4+nt] = __builtin_amdgcn_mfma_f32_16x16x32_bf16(af, bfr[nt], acc1[mt*4+nt], 0, 0, 0);
    }
  }
  #pragma unroll
  for (int mt = 0; mt < 4; mt++){
    int f0 = mt*16 + quad*4;
    f32x4 bv = *(const f32x4*)&b10[f0];
    #pragma unroll
    for (int nt = 0; nt < 4; nt++){
      int n = wid*64 + nt*16 + col;
      f32x4 a = acc1[mt*4+nt];
      uint2 o = { pk2(lrelu(a[0]+bv[0]), lrelu(a[1]+bv[1])),
                  pk2(lrelu(a[2]+bv[2]), lrelu(a[3]+bv[3])) };
      *(uint2*)&Bt[n][f0] = o;
    }
  }
  f32x4 acc2[16];
  #pragma unroll
  for (int i = 0; i < 16; i++) acc2[i] = z4;
  #pragma unroll
  for (int k0 = 0; k0 < 64; k0 += 32){
    bh8 bfr[4];
    #pragma unroll
    for (int nt = 0; nt < 4; nt++)
      bfr[nt] = *(const bh8*)&Bt[wid*64 + nt*16 + col][k0 + quad*8];
    #pragma unroll
    for (int mt = 0; mt < 4; mt++){
      bh8 af = *(const bh8*)&wA[1][mt*16 + col][k0 + quad*8];
      #pragma unroll
      for (int nt = 0; nt < 4; nt++)
        acc2[mt*4+nt] = __builtin_amdgcn_mfma_f32_16x16x32_bf16(af, bfr[nt], acc2[mt*4+nt], 0, 0, 0);
    }
  }
  float psA[4] = {0.f,0.f,0.f,0.f}, psB[4] = {0.f,0.f,0.f,0.f};
  #pragma unroll
  for (int mt = 0; mt < 4; mt++){
    int f0 = mt*16 + quad*4;
    f32x4 b11v = *(const f32x4*)&b11[f0];
    f32x4 wsv  = *(const f32x4*)&ws2[f0];
    f32x4 w20v = *(const f32x4*)&w20[f0];
    #pragma unroll
    for (int nt = 0; nt < 4; nt++){
      int lg = l0 + wid*64 + nt*16 + col;
      size_t base = ((size_t)b*C_ + f0)*L_ + lg;
      f32x4 a = acc2[mt*4+nt];
      #pragma unroll
      for (int r = 0; r < 4; r++){
        float xv = x[base + (size_t)r*L_];
        float lat = xv + 0.1f*(a[r] + b11v[r]);
        psA[nt] += wsv[r]*lat;
        psB[nt] += w20v[r]*lrelu(lat);
      }
    }
  }
  #pragma unroll
  for (int nt = 0; nt < 4; nt++){
    psA[nt] += __shfl_xor(psA[nt], 16); psA[nt] += __shfl_xor(psA[nt], 32);
    psB[nt] += __shfl_xor(psB[nt], 16); psB[nt] += __shfl_xor(psB[nt], 32);
  }
  if (quad == 0){
    float b20s = b20[0], w21s = w21[0], b21s = b21[0];
    #pragma unroll
    for (int nt = 0; nt < 4; nt++){
      float dx2 = w21s*lrelu(psB[nt] + b20s) + b21s;
      out[(size_t)b*L_ + l0 + wid*64 + nt*16 + col] = psA[nt] + 0.1f*dx2;
    }
  }
}

extern "C" void kernel_launch(void* const* d_in, const int* in_sizes, int n_in,
                              void* d_out, int out_size, void* d_ws, size_t ws_size,
                              hipStream_t stream) {
  (void)in_sizes; (void)n_in; (void)out_size; (void)ws_size;
  const float* codes   = (const float*)d_in[0];
  const int*   y       = (const int*)  d_in[1];
  const float* fc_w    = (const float*)d_in[2];
  const float* fc_b    = (const float*)d_in[3];
  const float* in_w0   = (const float*)d_in[4];
  const float* in_b0   = (const float*)d_in[5];
  const float* in_w1   = (const float*)d_in[6];
  const float* in_b1   = (const float*)d_in[7];
  const float* in_wsp  = (const float*)d_in[8];
  const float* leak    = (const float*)d_in[9];
  const float* hyper_w = (const float*)d_in[10];
  const float* hyper_b = (const float*)d_in[11];
  const float* out_w0  = (const float*)d_in[12];
  const float* out_b0  = (const float*)d_in[13];
  const float* out_w1  = (const float*)d_in[14];
  const float* out_b1  = (const float*)d_in[15];
  const float* l1_w0   = (const float*)d_in[16];
  const float* l1_b0   = (const float*)d_in[17];
  const float* l1_w1   = (const float*)d_in[18];
  const float* l1_b1   = (const float*)d_in[19];
  const float* l2_w0   = (const float*)d_in[20];
  const float* l2_b0   = (const float*)d_in[21];
  const float* l2_w1   = (const float*)d_in[22];
  const float* l2_b1   = (const float*)d_in[23];
  const float* l2_ws   = (const float*)d_in[24];
  float* out = (float*)d_out;

  char* ws = (char*)d_ws;
  unsigned short* p_bf = (unsigned short*)(ws);              // 18,972,672 B
  unsigned short* ybf  = (unsigned short*)(ws + 18972672);   // 131,072 B
  float* x             = (float*)(ws + 19103744);            // 33,554,432 B
  unsigned short* t1bf = (unsigned short*)(ws + 52658176);   // 16,777,216 B (outside loop)

  k_yemb<<<B_, 256, 0, stream>>>(fc_w, fc_b, y, ybf, out);
  k_hyper<<<PT_/64, 256, 0, stream>>>(hyper_w, hyper_b, ybf, p_bf);
  k_conv_in1<<<dim3(B_, 4), 256, 0, stream>>>(codes, in_w0, in_b0, t1bf);
  k_conv_in2<<<dim3(B_, 4), 256, 0, stream>>>(codes, in_wsp, in_w1, in_b1, t1bf, x);
  for (int it = 0; it < 8; ++it){
    k_iter<<<B_, 512, 0, stream>>>(x, p_bf, leak);
  }
  k_conv_out1<<<dim3(B_, 4), 256, 0, stream>>>(x, out_w0, out_b0, t1bf);
  k_conv_out2<<<dim3(B_, 2), 256, 0, stream>>>(x, t1bf, out_w1, out_b1);
  k_loss<<<dim3(B_, 2), 256, 0, stream>>>(x, codes, out);
  k_lat<<<dim3(B_, 2), 256, 0, stream>>>(x, l1_w0, l1_b0, l1_w1, l1_b1,
                                         l2_w0, l2_b0, l2_w1, l2_b1, l2_ws, out);
}